// Round 1
// baseline (149.851 us; speedup 1.0000x reference)
//
#include <hip/hip_runtime.h>
#include <cstdint>

#define PI_F 3.14159265358979323846f

typedef float v2f __attribute__((ext_vector_type(2)));

__device__ __forceinline__ float fract_(float x)  { return __builtin_amdgcn_fractf(x); }
__device__ __forceinline__ float sin2pi_(float r) { return __builtin_amdgcn_sinf(r); }  // sin(2*pi*r)
__device__ __forceinline__ float cos2pi_(float r) { return __builtin_amdgcn_cosf(r); }  // cos(2*pi*r)
__device__ __forceinline__ v2f  splat2(float x)   { v2f r; r.x = x; r.y = x; return r; }

// ---------------------------------------------------------------------------
// Single fused kernel. Structural changes vs round-5 (FP trajectory
// bit-identical, every expression/seed/fold-order verbatim):
//
//  1. k-chunk moved from WAVE axis to LANE-GROUP axis: wave w owns 16 items;
//     lane = cw*16 + il, chunk cw in [0,4) handles k in [cw*64, cw*64+64).
//     Cross-chunk reduce is 2x __shfl_xor (16 then 32). By commutativity of
//     fp32 add this reproduces the reference fold (S0+S1)+(S2+S3) bit-exactly
//     on every lane. -> ZERO __syncthreads in the 10-step loop, no red[] LDS,
//     waves fully independent (was 20 whole-block barriers at 2 blocks/CU).
//
//  2. pack_signs kernel FUSED away: each thread packs its own 64 k's per
//     component (32 float4 loads, identical comparisons and bit positions to
//     the old pre-pass -> identical words). Saves one 67MB dispatch + 2MB
//     workspace round-trip + a graph node.
// ---------------------------------------------------------------------------
extern "C" __global__ void __launch_bounds__(256)
refine(const float* __restrict__ th0, const float* __restrict__ r0,
       const float* __restrict__ a_th_raw, const float* __restrict__ a_r_raw,
       const float* __restrict__ l_th_raw, const float* __restrict__ l_r_raw,
       const float4* __restrict__ zr4, const float4* __restrict__ zi4,
       float* __restrict__ out) {
    const int lane = threadIdx.x & 63;
    const int w    = threadIdx.x >> 6;       // wave id 0..3: owns 16 items
    const int il   = lane & 15;              // item-in-wave
    const int cw   = lane >> 4;              // k-chunk 0..3: k in [cw*64, cw*64+64)
    const int item = blockIdx.x * 64 + w * 16 + il;

    __shared__ float sp[4][10];              // ath, ar, lth, lr per step

    if (threadIdx.x < 40) {
        const int a = threadIdx.x / 10, i = threadIdx.x % 10;
        const float* src = (a == 0) ? a_th_raw : (a == 1) ? a_r_raw
                         : (a == 2) ? l_th_raw : l_r_raw;
        const float v  = log1pf(expf(src[i]));           // verbatim round-1 expr
        const float hi = (a < 2) ? 0.2f : 1.0f;
        sp[a][i] = fminf(fmaxf(v, 1e-6f), hi);
    }

    // ---- inline sign-pack: this thread's 64 k's per component -------------
    // word n (n=0,1) bit m = sign(z[item*256 + cw*64 + 32n + m]) < 0,
    // identical bit layout to the old pack_signs output.
    const float4* za = zr4 + (size_t)item * 64 + (size_t)cw * 16;
    const float4* zb = zi4 + (size_t)item * 64 + (size_t)cw * 16;
    uint32_t br0 = 0u, br1 = 0u, bi0 = 0u, bi1 = 0u;
    #pragma unroll
    for (int q = 0; q < 8; ++q) {
        const float4 a0 = za[q];
        const float4 a1 = za[q + 8];
        const float4 b0 = zb[q];
        const float4 b1 = zb[q + 8];
        br0 |= ((uint32_t)(a0.x < 0.f) << (4 * q))     | ((uint32_t)(a0.y < 0.f) << (4 * q + 1))
             | ((uint32_t)(a0.z < 0.f) << (4 * q + 2)) | ((uint32_t)(a0.w < 0.f) << (4 * q + 3));
        br1 |= ((uint32_t)(a1.x < 0.f) << (4 * q))     | ((uint32_t)(a1.y < 0.f) << (4 * q + 1))
             | ((uint32_t)(a1.z < 0.f) << (4 * q + 2)) | ((uint32_t)(a1.w < 0.f) << (4 * q + 3));
        bi0 |= ((uint32_t)(b0.x < 0.f) << (4 * q))     | ((uint32_t)(b0.y < 0.f) << (4 * q + 1))
             | ((uint32_t)(b0.z < 0.f) << (4 * q + 2)) | ((uint32_t)(b0.w < 0.f) << (4 * q + 3));
        bi1 |= ((uint32_t)(b1.x < 0.f) << (4 * q))     | ((uint32_t)(b1.y < 0.f) << (4 * q + 1))
             | ((uint32_t)(b1.z < 0.f) << (4 * q + 2)) | ((uint32_t)(b1.w < 0.f) << (4 * q + 3));
    }

    // u0 = atanh(theta/60), u1 = atanh(2*(r/2000)-1), with reference clips
    float y = th0[item] * (1.0f / 60.0f);
    y = fminf(fmaxf(y, -1.0f + 1e-6f), 1.0f - 1e-6f);
    float u0 = atanhf(y);
    float sR = r0[item] * (1.0f / 2000.0f);
    sR = fminf(fmaxf(sR, 1e-6f), 1.0f - 1e-6f);
    float u1 = atanhf(2.0f * sR - 1.0f);

    const float w64 = (float)(cw * 64);

    __syncthreads();                          // sp[] ready (only barrier)

    for (int t = 0; t < 10; ++t) {
        const float ath = sp[0][t], ar = sp[1][t], lth = sp[2][t], lr = sp[3][t];

        const float T0 = tanhf(u0), T1 = tanhf(u1);
        const float th_rad = (PI_F / 3.0f) * T0;          // 60*T0 deg -> rad
        const float sth = sinf(th_rad), cth = cosf(th_rad);
        const float r   = 1000.0f * (T1 + 1.0f);
        const float crev = 0.5f * sth - 2e-4f * r;        // revolutions per unit k

        // rotation step e^{i*2pi*4*crev}
        const float d4 = fract_(4.0f * crev);
        const v2f C4 = splat2(cos2pi_(d4));
        const v2f S4 = splat2(sin2pi_(d4));

        // chain pairs: pair p holds chains (2p, 2p+1)
        v2f c[2], s[2], kf[2], acc[2];
        #pragma unroll
        for (int p2 = 0; p2 < 2; ++p2) {
            const float k0a = w64 + (float)(2 * p2);
            const float k0b = w64 + (float)(2 * p2 + 1);
            const float rva = fract_(k0a * crev);
            const float rvb = fract_(k0b * crev);
            v2f cc, ssv, kk;
            cc.x  = cos2pi_(rva);  cc.y  = cos2pi_(rvb);
            ssv.x = sin2pi_(rva);  ssv.y = sin2pi_(rvb);
            kk.x  = k0a;           kk.y  = k0b;
            c[p2]   = cc;
            s[p2]   = ssv;
            kf[p2]  = kk;
            acc[p2] = splat2(0.0f);
        }

        const v2f mtwo = splat2(-2.0f);
        const v2f one  = splat2(1.0f);
        const v2f cub  = splat2(-(1.0f / 196608.0f));
        const v2f four = splat2(4.0f);

        #pragma unroll
        for (int j = 0; j < 16; ++j) {
            #pragma unroll
            for (int p2 = 0; p2 < 2; ++p2) {
                const int klA = 2 * p2 + 4 * j;            // chains 2p2, 2p2+1
                const int klB = klA + 1;                   // compile-time
                const uint32_t wr = (klA < 32) ? br0 : br1;
                const uint32_t wi = (klA < 32) ? bi0 : bi1;
                const uint32_t mreA = (wr << (31 - (klA & 31))) & 0x80000000u;
                const uint32_t mreB = (wr << (31 - (klB & 31))) & 0x80000000u;
                const uint32_t mimA = (wi << (31 - (klA & 31))) & 0x80000000u;
                const uint32_t mimB = (wi << (31 - (klB & 31))) & 0x80000000u;
                const v2f cs = c[p2], ss = s[p2];
                v2f zc, zs;                                 // z_im*cos, z_re*sin
                zc.x = __uint_as_float(__float_as_uint(cs.x) ^ mimA);
                zc.y = __uint_as_float(__float_as_uint(cs.y) ^ mimB);
                zs.x = __uint_as_float(__float_as_uint(ss.x) ^ mreA);
                zs.y = __uint_as_float(__float_as_uint(ss.y) ^ mreB);
                const v2f w0 = zc - zs;
                // cubic sigma term: -sin(4phi)/786432 = -s*c*(1-2s^2)/196608
                const v2f u2 = ss * ss;
                const v2f t2 = __builtin_elementwise_fma(mtwo, u2, one);
                const v2f sc = ss * cs;
                const v2f v  = sc * t2;
                const v2f W  = __builtin_elementwise_fma(v, cub, w0 * 0.0625f);
                acc[p2] = __builtin_elementwise_fma(kf[p2], W, acc[p2]);
                kf[p2]  = kf[p2] + four;
                // rotate phase by 4*crev revolutions
                const v2f tA = ss * S4;
                const v2f tB = cs * S4;
                c[p2] = __builtin_elementwise_fma(cs, C4, -tA);
                s[p2] = __builtin_elementwise_fma(ss, C4, tB);
            }
        }
        // round-1 fold: (acc0 + acc1) + (acc2 + acc3)
        float S = (acc[0].x + acc[0].y) + (acc[1].x + acc[1].y);

        // cross-chunk reduce, now intra-wave: xor-16 then xor-32.
        // Bit-identical to (S0+S1)+(S2+S3) on every lane by fp-add
        // commutativity (x+y == y+x exactly).
        S += __shfl_xor(S, 16, 64);
        S += __shfl_xor(S, 32, 64);

        // gradient of -loglike wrt u, then normalized clipped step (verbatim)
        const float g0 = -(PI_F * PI_F / 3.0f) * cth * (1.0f - T0 * T0) * S;
        const float g1 = 0.4f * PI_F * (1.0f - T1 * T1) * S;
        const float den0 = fmaxf(fabsf(g0), 1e-6f) + lth;
        const float den1 = fmaxf(fabsf(g1), 1e-6f) + lr;
        float st0 = ath * g0 / den0;
        float st1 = ar  * g1 / den1;
        st0 = fminf(fmaxf(st0, -0.1f), 0.1f);
        st1 = fminf(fmaxf(st1, -0.1f), 0.1f);
        u0 -= st0;
        u1 -= st1;
    }

    if (cw == 0) {
        const float thT = 60.0f * tanhf(u0);
        const float rT  = 1000.0f * (tanhf(u1) + 1.0f);
        reinterpret_cast<float2*>(out)[item] = make_float2(thT, rT);
    }
}

extern "C" void kernel_launch(void* const* d_in, const int* in_sizes, int n_in,
                              void* d_out, int out_size, void* d_ws, size_t ws_size,
                              hipStream_t stream) {
    const float* zr   = (const float*)d_in[0];
    const float* zi   = (const float*)d_in[1];
    const float* th0  = (const float*)d_in[2];
    const float* r0   = (const float*)d_in[3];
    const float* athr = (const float*)d_in[4];
    const float* arr  = (const float*)d_in[5];
    const float* lthr = (const float*)d_in[6];
    const float* lrr  = (const float*)d_in[7];

    const int B = in_sizes[2];          // 32768

    refine<<<B / 64, 256, 0, stream>>>(th0, r0, athr, arr, lthr, lrr,
                                       (const float4*)zr, (const float4*)zi,
                                       (float*)d_out);
}

// Round 2
// 140.365 us; speedup vs baseline: 1.0676x; 1.0676x over previous
//
#include <hip/hip_runtime.h>
#include <cstdint>

#define PI_F 3.14159265358979323846f

typedef float v2f __attribute__((ext_vector_type(2)));

__device__ __forceinline__ float fract_(float x)  { return __builtin_amdgcn_fractf(x); }
__device__ __forceinline__ float sin2pi_(float r) { return __builtin_amdgcn_sinf(r); }  // sin(2*pi*r)
__device__ __forceinline__ float cos2pi_(float r) { return __builtin_amdgcn_cosf(r); }  // cos(2*pi*r)
__device__ __forceinline__ v2f  splat2(float x)   { v2f r; r.x = x; r.y = x; return r; }

// ---------------------------------------------------------------------------
// Kernel A: ballot-based sign pack. One WAVE per item: lane l loads float4 at
// row offset 4l -> the wave reads the item's 256-float row CONTIGUOUSLY
// (1 KB per load instruction, perfect coalescing; was 64 scattered lines per
// instruction at ~0.9 TB/s). __ballot(v.x<0) gives bit l = sign z[4l+0] --
// and k mod 4 is exactly the chain axis of the refiner, so the four ballots
// per component are the four chain masks. Lanes 0..15 assemble 8 words per
// item per component in CHAIN-MAJOR layout:
//   word(cw,h) = pr[item*8 + cw*2 + h],
//   low  16 bits: bit j = sign zr[item*256 + 64cw + 4j + 2h    ]
//   high 16 bits: bit j = sign zr[item*256 + 64cw + 4j + 2h + 1]
// (i.e. the two chains 2h, 2h+1 of chunk cw, step j = 0..15).
// ---------------------------------------------------------------------------
extern "C" __global__ void __launch_bounds__(256)
pack_signs(const float4* __restrict__ zr4, const float4* __restrict__ zi4,
           uint32_t* __restrict__ pr, uint32_t* __restrict__ pim) {
    const int lane = threadIdx.x & 63;
    const int w    = threadIdx.x >> 6;
    const int item = blockIdx.x * 4 + w;

    const float4 fr = zr4[(size_t)item * 64 + lane];
    const float4 fi = zi4[(size_t)item * 64 + lane];

    const uint64_t Mr0 = __ballot(fr.x < 0.f);   // chain 0: k = 4l
    const uint64_t Mr1 = __ballot(fr.y < 0.f);   // chain 1: k = 4l+1
    const uint64_t Mr2 = __ballot(fr.z < 0.f);   // chain 2
    const uint64_t Mr3 = __ballot(fr.w < 0.f);   // chain 3
    const uint64_t Mi0 = __ballot(fi.x < 0.f);
    const uint64_t Mi1 = __ballot(fi.y < 0.f);
    const uint64_t Mi2 = __ballot(fi.z < 0.f);
    const uint64_t Mi3 = __ballot(fi.w < 0.f);

    if (lane < 16) {
        const int comp = lane >> 3;              // 0: re, 1: im
        const int sub  = lane & 7;               // word index 0..7
        const int cw   = sub >> 1;               // chunk
        const int h    = sub & 1;                // chain-pair half
        const uint64_t ma = comp ? (h ? Mi2 : Mi0) : (h ? Mr2 : Mr0);
        const uint64_t mb = comp ? (h ? Mi3 : Mi1) : (h ? Mr3 : Mr1);
        const int sh = 16 * cw;
        const uint32_t word = ((uint32_t)(ma >> sh) & 0xFFFFu)
                            | (((uint32_t)(mb >> sh) & 0xFFFFu) << 16);
        uint32_t* dst = comp ? pim : pr;
        dst[(size_t)item * 8 + sub] = word;
    }
}

// ---------------------------------------------------------------------------
// Kernel B: refiner. FP trajectory bit-identical to the 36.0-absmax baseline;
// structural change: the 4 chains of each k-chunk are split across 2 LANES
// (lane sub = cw*2+h owns chain pair (2h, 2h+1) of chunk cw, ONE v2f pair,
// 16 j-steps). 8 lanes per item -> wave owns 8 items -> grid doubles to 1024
// blocks = 16 waves/CU (was 8), attacking the 17% occupancy / 45% VALUBusy
// latency limit. Reduce is 3x shfl_xor (8,16,32):
//   xor8 : A_{2h}+A_{2h+1} pairs ->  (A0+A1)+(A2+A3)      [= old chunk fold]
//   xor16/32: (S0+S1)+(S2+S3) across chunks               [= old cross fold]
// every regrouping is a pure fp-add commutation -> bit-exact.
// ---------------------------------------------------------------------------
extern "C" __global__ void __launch_bounds__(256)
refine(const float* __restrict__ th0, const float* __restrict__ r0,
       const float* __restrict__ a_th_raw, const float* __restrict__ a_r_raw,
       const float* __restrict__ l_th_raw, const float* __restrict__ l_r_raw,
       const uint32_t* __restrict__ pr, const uint32_t* __restrict__ pim,
       float* __restrict__ out) {
    const int lane = threadIdx.x & 63;
    const int w    = threadIdx.x >> 6;       // wave id 0..3: owns 8 items
    const int il   = lane & 7;               // item-in-wave
    const int sub  = lane >> 3;              // 0..7
    const int cw   = sub >> 1;               // k-chunk: k in [cw*64, cw*64+64)
    const int h    = sub & 1;                // chain pair (2h, 2h+1)
    const int item = blockIdx.x * 32 + w * 8 + il;

    __shared__ float sp[4][10];              // ath, ar, lth, lr per step

    if (threadIdx.x < 40) {
        const int a = threadIdx.x / 10, i = threadIdx.x % 10;
        const float* src = (a == 0) ? a_th_raw : (a == 1) ? a_r_raw
                         : (a == 2) ? l_th_raw : l_r_raw;
        const float v  = log1pf(expf(src[i]));           // verbatim round-1 expr
        const float hi = (a < 2) ? 0.2f : 1.0f;
        sp[a][i] = fminf(fmaxf(v, 1e-6f), hi);
    }

    // this thread's sign words (chain-major layout from pack_signs)
    const uint32_t br = pr [(size_t)item * 8 + sub];
    const uint32_t bi = pim[(size_t)item * 8 + sub];

    // u0 = atanh(theta/60), u1 = atanh(2*(r/2000)-1), with reference clips
    float y = th0[item] * (1.0f / 60.0f);
    y = fminf(fmaxf(y, -1.0f + 1e-6f), 1.0f - 1e-6f);
    float u0 = atanhf(y);
    float sR = r0[item] * (1.0f / 2000.0f);
    sR = fminf(fmaxf(sR, 1e-6f), 1.0f - 1e-6f);
    float u1 = atanhf(2.0f * sR - 1.0f);

    // chain-pair k seeds: exact small ints, identical values to baseline's
    // w64 + (float)(2*p2) / +1
    const float k0a = (float)(cw * 64 + 2 * h);
    const float k0b = (float)(cw * 64 + 2 * h + 1);

    __syncthreads();                          // sp[] ready (only barrier)

    for (int t = 0; t < 10; ++t) {
        const float ath = sp[0][t], ar = sp[1][t], lth = sp[2][t], lr = sp[3][t];

        const float T0 = tanhf(u0), T1 = tanhf(u1);
        const float th_rad = (PI_F / 3.0f) * T0;          // 60*T0 deg -> rad
        const float sth = sinf(th_rad), cth = cosf(th_rad);
        const float r   = 1000.0f * (T1 + 1.0f);
        const float crev = 0.5f * sth - 2e-4f * r;        // revolutions per unit k

        // rotation step e^{i*2pi*4*crev}
        const float d4 = fract_(4.0f * crev);
        const v2f C4 = splat2(cos2pi_(d4));
        const v2f S4 = splat2(sin2pi_(d4));

        // seed the single chain pair (chains 2h, 2h+1 of chunk cw)
        const float rva = fract_(k0a * crev);
        const float rvb = fract_(k0b * crev);
        v2f c, s, kf, acc;
        c.x  = cos2pi_(rva);  c.y  = cos2pi_(rvb);
        s.x  = sin2pi_(rva);  s.y  = sin2pi_(rvb);
        kf.x = k0a;           kf.y = k0b;
        acc  = splat2(0.0f);

        const v2f mtwo = splat2(-2.0f);
        const v2f one  = splat2(1.0f);
        const v2f cub  = splat2(-(1.0f / 196608.0f));
        const v2f four = splat2(4.0f);

        #pragma unroll
        for (int j = 0; j < 16; ++j) {
            // chain A bit = j, chain B bit = 16+j  (compile-time shifts)
            const uint32_t mreA = (br << (31 - j)) & 0x80000000u;
            const uint32_t mreB = (br << (15 - j)) & 0x80000000u;
            const uint32_t mimA = (bi << (31 - j)) & 0x80000000u;
            const uint32_t mimB = (bi << (15 - j)) & 0x80000000u;
            const v2f cs = c, ss = s;
            v2f zc, zs;                                 // z_im*cos, z_re*sin
            zc.x = __uint_as_float(__float_as_uint(cs.x) ^ mimA);
            zc.y = __uint_as_float(__float_as_uint(cs.y) ^ mimB);
            zs.x = __uint_as_float(__float_as_uint(ss.x) ^ mreA);
            zs.y = __uint_as_float(__float_as_uint(ss.y) ^ mreB);
            const v2f w0 = zc - zs;
            // cubic sigma term: -sin(4phi)/786432 = -s*c*(1-2s^2)/196608
            const v2f u2 = ss * ss;
            const v2f t2 = __builtin_elementwise_fma(mtwo, u2, one);
            const v2f sc = ss * cs;
            const v2f v  = sc * t2;
            const v2f W  = __builtin_elementwise_fma(v, cub, w0 * 0.0625f);
            acc = __builtin_elementwise_fma(kf, W, acc);
            kf  = kf + four;
            // rotate phase by 4*crev revolutions
            const v2f tA = ss * S4;
            const v2f tB = cs * S4;
            c = __builtin_elementwise_fma(cs, C4, -tA);
            s = __builtin_elementwise_fma(ss, C4, tB);
        }
        // within-pair fold: A_{2h} + A_{2h+1}
        float S = acc.x + acc.y;
        // xor8: -> (A0+A1)+(A2+A3) = old chunk fold (commutation-exact)
        S += __shfl_xor(S, 8, 64);
        // xor16/32: -> (S0+S1)+(S2+S3) across chunks (commutation-exact)
        S += __shfl_xor(S, 16, 64);
        S += __shfl_xor(S, 32, 64);

        // gradient of -loglike wrt u, then normalized clipped step (verbatim)
        const float g0 = -(PI_F * PI_F / 3.0f) * cth * (1.0f - T0 * T0) * S;
        const float g1 = 0.4f * PI_F * (1.0f - T1 * T1) * S;
        const float den0 = fmaxf(fabsf(g0), 1e-6f) + lth;
        const float den1 = fmaxf(fabsf(g1), 1e-6f) + lr;
        float st0 = ath * g0 / den0;
        float st1 = ar  * g1 / den1;
        st0 = fminf(fmaxf(st0, -0.1f), 0.1f);
        st1 = fminf(fmaxf(st1, -0.1f), 0.1f);
        u0 -= st0;
        u1 -= st1;
    }

    if (sub == 0) {
        const float thT = 60.0f * tanhf(u0);
        const float rT  = 1000.0f * (tanhf(u1) + 1.0f);
        reinterpret_cast<float2*>(out)[item] = make_float2(thT, rT);
    }
}

extern "C" void kernel_launch(void* const* d_in, const int* in_sizes, int n_in,
                              void* d_out, int out_size, void* d_ws, size_t ws_size,
                              hipStream_t stream) {
    const float* zr   = (const float*)d_in[0];
    const float* zi   = (const float*)d_in[1];
    const float* th0  = (const float*)d_in[2];
    const float* r0   = (const float*)d_in[3];
    const float* athr = (const float*)d_in[4];
    const float* arr  = (const float*)d_in[5];
    const float* lthr = (const float*)d_in[6];
    const float* lrr  = (const float*)d_in[7];

    const int B = in_sizes[2];          // 32768

    uint32_t* pr  = (uint32_t*)d_ws;     // B*8 words = 1 MB
    uint32_t* pim = pr + (size_t)B * 8;  // B*8 words = 1 MB

    pack_signs<<<B / 4, 256, 0, stream>>>((const float4*)zr, (const float4*)zi,
                                          pr, pim);
    refine<<<B / 32, 256, 0, stream>>>(th0, r0, athr, arr, lthr, lrr,
                                       pr, pim, (float*)d_out);
}

// Round 3
// 138.506 us; speedup vs baseline: 1.0819x; 1.0134x over previous
//
#include <hip/hip_runtime.h>
#include <cstdint>

#define PI_F 3.14159265358979323846f

typedef float v2f __attribute__((ext_vector_type(2)));

__device__ __forceinline__ float fract_(float x)  { return __builtin_amdgcn_fractf(x); }
__device__ __forceinline__ float sin2pi_(float r) { return __builtin_amdgcn_sinf(r); }  // sin(2*pi*r)
__device__ __forceinline__ float cos2pi_(float r) { return __builtin_amdgcn_cosf(r); }  // cos(2*pi*r)
__device__ __forceinline__ v2f  splat2(float x)   { v2f r; r.x = x; r.y = x; return r; }

// ---------------------------------------------------------------------------
// Kernel A: ballot-based sign pack (verbatim round-2, proven). One WAVE per
// item; lane l loads float4 at row offset 4l -> contiguous 1KB/instr reads.
// Chain-major output layout:
//   word(cw,h) = pr[item*8 + cw*2 + h]
//   low  16 bits: bit j = sign z[item*256 + 64cw + 4j + 2h    ]
//   high 16 bits: bit j = sign z[item*256 + 64cw + 4j + 2h + 1]
// ---------------------------------------------------------------------------
extern "C" __global__ void __launch_bounds__(256)
pack_signs(const float4* __restrict__ zr4, const float4* __restrict__ zi4,
           uint32_t* __restrict__ pr, uint32_t* __restrict__ pim) {
    const int lane = threadIdx.x & 63;
    const int w    = threadIdx.x >> 6;
    const int item = blockIdx.x * 4 + w;

    const float4 fr = zr4[(size_t)item * 64 + lane];
    const float4 fi = zi4[(size_t)item * 64 + lane];

    const uint64_t Mr0 = __ballot(fr.x < 0.f);   // chain 0: k = 4l
    const uint64_t Mr1 = __ballot(fr.y < 0.f);   // chain 1: k = 4l+1
    const uint64_t Mr2 = __ballot(fr.z < 0.f);   // chain 2
    const uint64_t Mr3 = __ballot(fr.w < 0.f);   // chain 3
    const uint64_t Mi0 = __ballot(fi.x < 0.f);
    const uint64_t Mi1 = __ballot(fi.y < 0.f);
    const uint64_t Mi2 = __ballot(fi.z < 0.f);
    const uint64_t Mi3 = __ballot(fi.w < 0.f);

    if (lane < 16) {
        const int comp = lane >> 3;              // 0: re, 1: im
        const int sub  = lane & 7;               // word index 0..7
        const int cw   = sub >> 1;               // chunk
        const int h    = sub & 1;                // chain-pair half
        const uint64_t ma = comp ? (h ? Mi2 : Mi0) : (h ? Mr2 : Mr0);
        const uint64_t mb = comp ? (h ? Mi3 : Mi1) : (h ? Mr3 : Mr1);
        const int sh = 16 * cw;
        const uint32_t word = ((uint32_t)(ma >> sh) & 0xFFFFu)
                            | (((uint32_t)(mb >> sh) & 0xFFFFu) << 16);
        uint32_t* dst = comp ? pim : pr;
        dst[(size_t)item * 8 + sub] = word;
    }
}

// ---------------------------------------------------------------------------
// Kernel B: refiner. FP trajectory bit-identical to the 36.0-absmax baseline.
// Round-3 change: the per-j sign plumbing (4 shifts + 4 ands + 4 xors +
// w0*0.0625 = 13 ops) is replaced by 4 v_fma_mix_f32 using PRECOMPUTED
// packed-f16 constants pm = z * 0.0625 (t-invariant, 32 VGPRs as raw bits):
//   m1  = pmI(f16)*cs + 0      -- +-2^-4 * cs is an EXACT scale, +0 exact
//   w0' = -pmR(f16)*ss + m1    -- single-rounding fma of two exact addends
// round(2^-4 * x) == 2^-4 * round(x) for our value range, so w0' is
// bit-identical to the baseline's round(zc - zs) * 0.0625. j-body 25 -> 15
// VALU ops (-40% of the dominant loop). Inline asm (not (float)half casts)
// prevents LICM from hoisting 64 f16->f32 converts into 64 live registers.
// ---------------------------------------------------------------------------
extern "C" __global__ void __launch_bounds__(256)
refine(const float* __restrict__ th0, const float* __restrict__ r0,
       const float* __restrict__ a_th_raw, const float* __restrict__ a_r_raw,
       const float* __restrict__ l_th_raw, const float* __restrict__ l_r_raw,
       const uint32_t* __restrict__ pr, const uint32_t* __restrict__ pim,
       float* __restrict__ out) {
    const int lane = threadIdx.x & 63;
    const int w    = threadIdx.x >> 6;       // wave id 0..3: owns 8 items
    const int il   = lane & 7;               // item-in-wave
    const int sub  = lane >> 3;              // 0..7
    const int cw   = sub >> 1;               // k-chunk: k in [cw*64, cw*64+64)
    const int h    = sub & 1;                // chain pair (2h, 2h+1)
    const int item = blockIdx.x * 32 + w * 8 + il;

    __shared__ float sp[4][10];              // ath, ar, lth, lr per step

    if (threadIdx.x < 40) {
        const int a = threadIdx.x / 10, i = threadIdx.x % 10;
        const float* src = (a == 0) ? a_th_raw : (a == 1) ? a_r_raw
                         : (a == 2) ? l_th_raw : l_r_raw;
        const float v  = log1pf(expf(src[i]));           // verbatim round-1 expr
        const float hi = (a < 2) ? 0.2f : 1.0f;
        sp[a][i] = fminf(fmaxf(v, 1e-6f), hi);
    }

    // this thread's sign words (chain-major layout from pack_signs)
    const uint32_t br = pr [(size_t)item * 8 + sub];
    const uint32_t bi = pim[(size_t)item * 8 + sub];

    // Precompute pm = z * 0.0625 as packed f16 bit patterns (t-invariant).
    // f16 +0.0625 = 0x2C00; sign bit j of br -> low-half sign (chain A),
    // bit 16+j -> high-half sign (chain B); both land via one shift (15-j).
    uint32_t pmR2[16], pmI2[16];
    #pragma unroll
    for (int j = 0; j < 16; ++j) {
        const uint32_t tr = br << (15 - j);
        const uint32_t ti = bi << (15 - j);
        pmR2[j] = 0x2C002C00u | (tr & 0x80008000u);
        pmI2[j] = 0x2C002C00u | (ti & 0x80008000u);
    }

    // u0 = atanh(theta/60), u1 = atanh(2*(r/2000)-1), with reference clips
    float y = th0[item] * (1.0f / 60.0f);
    y = fminf(fmaxf(y, -1.0f + 1e-6f), 1.0f - 1e-6f);
    float u0 = atanhf(y);
    float sR = r0[item] * (1.0f / 2000.0f);
    sR = fminf(fmaxf(sR, 1e-6f), 1.0f - 1e-6f);
    float u1 = atanhf(2.0f * sR - 1.0f);

    // chain-pair k seeds: exact small ints, identical values to baseline
    const float k0a = (float)(cw * 64 + 2 * h);
    const float k0b = (float)(cw * 64 + 2 * h + 1);

    const float kZero = 0.0f;

    __syncthreads();                          // sp[] ready (only barrier)

    for (int t = 0; t < 10; ++t) {
        const float ath = sp[0][t], ar = sp[1][t], lth = sp[2][t], lr = sp[3][t];

        const float T0 = tanhf(u0), T1 = tanhf(u1);
        const float th_rad = (PI_F / 3.0f) * T0;          // 60*T0 deg -> rad
        const float sth = sinf(th_rad), cth = cosf(th_rad);
        const float r   = 1000.0f * (T1 + 1.0f);
        const float crev = 0.5f * sth - 2e-4f * r;        // revolutions per unit k

        // rotation step e^{i*2pi*4*crev}
        const float d4 = fract_(4.0f * crev);
        const v2f C4 = splat2(cos2pi_(d4));
        const v2f S4 = splat2(sin2pi_(d4));

        // seed the single chain pair (chains 2h, 2h+1 of chunk cw)
        const float rva = fract_(k0a * crev);
        const float rvb = fract_(k0b * crev);
        v2f c, s, kf, acc;
        c.x  = cos2pi_(rva);  c.y  = cos2pi_(rvb);
        s.x  = sin2pi_(rva);  s.y  = sin2pi_(rvb);
        kf.x = k0a;           kf.y = k0b;
        acc  = splat2(0.0f);

        const v2f mtwo = splat2(-2.0f);
        const v2f one  = splat2(1.0f);
        const v2f cub  = splat2(-(1.0f / 196608.0f));
        const v2f four = splat2(4.0f);

        #pragma unroll
        for (int j = 0; j < 16; ++j) {
            const v2f cs = c, ss = s;
            // w0' = pmI*cs - pmR*ss  (already scaled by 0.0625, bit-exact
            // vs baseline xor+sub+mul; see header comment)
            float m1x, m1y, w0x, w0y;
            asm("v_fma_mix_f32 %0, %1, %2, %3 op_sel_hi:[1,0,0]"
                : "=v"(m1x) : "v"(pmI2[j]), "v"(cs.x), "v"(kZero));
            asm("v_fma_mix_f32 %0, %1, %2, %3 op_sel:[1,0,0] op_sel_hi:[1,0,0]"
                : "=v"(m1y) : "v"(pmI2[j]), "v"(cs.y), "v"(kZero));
            asm("v_fma_mix_f32 %0, -%1, %2, %3 op_sel_hi:[1,0,0]"
                : "=v"(w0x) : "v"(pmR2[j]), "v"(ss.x), "v"(m1x));
            asm("v_fma_mix_f32 %0, -%1, %2, %3 op_sel:[1,0,0] op_sel_hi:[1,0,0]"
                : "=v"(w0y) : "v"(pmR2[j]), "v"(ss.y), "v"(m1y));
            v2f w0p; w0p.x = w0x; w0p.y = w0y;
            // cubic sigma term: -sin(4phi)/786432 = -s*c*(1-2s^2)/196608
            const v2f u2 = ss * ss;
            const v2f t2 = __builtin_elementwise_fma(mtwo, u2, one);
            const v2f sc = ss * cs;
            const v2f v  = sc * t2;
            const v2f W  = __builtin_elementwise_fma(v, cub, w0p);
            acc = __builtin_elementwise_fma(kf, W, acc);
            kf  = kf + four;
            // rotate phase by 4*crev revolutions
            const v2f tA = ss * S4;
            const v2f tB = cs * S4;
            c = __builtin_elementwise_fma(cs, C4, -tA);
            s = __builtin_elementwise_fma(ss, C4, tB);
        }
        // within-pair fold: A_{2h} + A_{2h+1}
        float S = acc.x + acc.y;
        // xor8: -> (A0+A1)+(A2+A3) = old chunk fold (commutation-exact)
        S += __shfl_xor(S, 8, 64);
        // xor16/32: -> (S0+S1)+(S2+S3) across chunks (commutation-exact)
        S += __shfl_xor(S, 16, 64);
        S += __shfl_xor(S, 32, 64);

        // gradient of -loglike wrt u, then normalized clipped step (verbatim)
        const float g0 = -(PI_F * PI_F / 3.0f) * cth * (1.0f - T0 * T0) * S;
        const float g1 = 0.4f * PI_F * (1.0f - T1 * T1) * S;
        const float den0 = fmaxf(fabsf(g0), 1e-6f) + lth;
        const float den1 = fmaxf(fabsf(g1), 1e-6f) + lr;
        float st0 = ath * g0 / den0;
        float st1 = ar  * g1 / den1;
        st0 = fminf(fmaxf(st0, -0.1f), 0.1f);
        st1 = fminf(fmaxf(st1, -0.1f), 0.1f);
        u0 -= st0;
        u1 -= st1;
    }

    if (sub == 0) {
        const float thT = 60.0f * tanhf(u0);
        const float rT  = 1000.0f * (tanhf(u1) + 1.0f);
        reinterpret_cast<float2*>(out)[item] = make_float2(thT, rT);
    }
}

extern "C" void kernel_launch(void* const* d_in, const int* in_sizes, int n_in,
                              void* d_out, int out_size, void* d_ws, size_t ws_size,
                              hipStream_t stream) {
    const float* zr   = (const float*)d_in[0];
    const float* zi   = (const float*)d_in[1];
    const float* th0  = (const float*)d_in[2];
    const float* r0   = (const float*)d_in[3];
    const float* athr = (const float*)d_in[4];
    const float* arr  = (const float*)d_in[5];
    const float* lthr = (const float*)d_in[6];
    const float* lrr  = (const float*)d_in[7];

    const int B = in_sizes[2];          // 32768

    uint32_t* pr  = (uint32_t*)d_ws;     // B*8 words = 1 MB
    uint32_t* pim = pr + (size_t)B * 8;  // B*8 words = 1 MB

    pack_signs<<<B / 4, 256, 0, stream>>>((const float4*)zr, (const float4*)zi,
                                          pr, pim);
    refine<<<B / 32, 256, 0, stream>>>(th0, r0, athr, arr, lthr, lrr,
                                       pr, pim, (float*)d_out);
}

// Round 4
// 133.893 us; speedup vs baseline: 1.1192x; 1.0345x over previous
//
#include <hip/hip_runtime.h>
#include <cstdint>

#define PI_F 3.14159265358979323846f

typedef float v2f __attribute__((ext_vector_type(2)));

__device__ __forceinline__ float fract_(float x)  { return __builtin_amdgcn_fractf(x); }
__device__ __forceinline__ float sin2pi_(float r) { return __builtin_amdgcn_sinf(r); }  // sin(2*pi*r)
__device__ __forceinline__ float cos2pi_(float r) { return __builtin_amdgcn_cosf(r); }  // cos(2*pi*r)
__device__ __forceinline__ v2f  splat2(float x)   { v2f r; r.x = x; r.y = x; return r; }

// ---------------------------------------------------------------------------
// Kernel A: ballot-based sign pack (verbatim round-2, proven ~10us, BW-bound).
// One WAVE per item; lane l loads float4 at row offset 4l -> contiguous
// 1KB/instr reads. Chain-major output layout:
//   word(cw,h) = pr[item*8 + cw*2 + h]
//   low  16 bits: bit j = sign z[item*256 + 64cw + 4j + 2h    ]
//   high 16 bits: bit j = sign z[item*256 + 64cw + 4j + 2h + 1]
// ---------------------------------------------------------------------------
extern "C" __global__ void __launch_bounds__(256)
pack_signs(const float4* __restrict__ zr4, const float4* __restrict__ zi4,
           uint32_t* __restrict__ pr, uint32_t* __restrict__ pim) {
    const int lane = threadIdx.x & 63;
    const int w    = threadIdx.x >> 6;
    const int item = blockIdx.x * 4 + w;

    const float4 fr = zr4[(size_t)item * 64 + lane];
    const float4 fi = zi4[(size_t)item * 64 + lane];

    const uint64_t Mr0 = __ballot(fr.x < 0.f);   // chain 0: k = 4l
    const uint64_t Mr1 = __ballot(fr.y < 0.f);   // chain 1: k = 4l+1
    const uint64_t Mr2 = __ballot(fr.z < 0.f);   // chain 2
    const uint64_t Mr3 = __ballot(fr.w < 0.f);   // chain 3
    const uint64_t Mi0 = __ballot(fi.x < 0.f);
    const uint64_t Mi1 = __ballot(fi.y < 0.f);
    const uint64_t Mi2 = __ballot(fi.z < 0.f);
    const uint64_t Mi3 = __ballot(fi.w < 0.f);

    if (lane < 16) {
        const int comp = lane >> 3;              // 0: re, 1: im
        const int sub  = lane & 7;               // word index 0..7
        const int cw   = sub >> 1;               // chunk
        const int h    = sub & 1;                // chain-pair half
        const uint64_t ma = comp ? (h ? Mi2 : Mi0) : (h ? Mr2 : Mr0);
        const uint64_t mb = comp ? (h ? Mi3 : Mi1) : (h ? Mr3 : Mr1);
        const int sh = 16 * cw;
        const uint32_t word = ((uint32_t)(ma >> sh) & 0xFFFFu)
                            | (((uint32_t)(mb >> sh) & 0xFFFFu) << 16);
        uint32_t* dst = comp ? pim : pr;
        dst[(size_t)item * 8 + sub] = word;
    }
}

// ---------------------------------------------------------------------------
// Kernel B: refiner. FP trajectory bit-identical to the 36.0-absmax baseline.
// Round-4 changes vs round-2 (round-3 mix-fma REVERTED -- it was issue-neutral
// but lengthened the critical path; VALU-busy time was identical):
//   h-SPLIT of the per-t head/tail. Lane h owns only u_h:
//    - ONE tanhf per t: T_own = tanhf(u_own) (uniform instruction on selected
//      operand -> genuine wave-level op reduction), T0/T1 redistributed with
//      one shfl_xor(8) (bit-copy).
//    - gradient/step tail computed once per lane for its own component with
//      the baseline's exact association ((C*cth)*(1-T^2))*S.
//    - epilogue: one tanhf, split scalar stores out[2*item+h].
//   All j-loop code, seeds, reduce order: verbatim round-2 -> bit-exact.
// ---------------------------------------------------------------------------
extern "C" __global__ void __launch_bounds__(256)
refine(const float* __restrict__ th0, const float* __restrict__ r0,
       const float* __restrict__ a_th_raw, const float* __restrict__ a_r_raw,
       const float* __restrict__ l_th_raw, const float* __restrict__ l_r_raw,
       const uint32_t* __restrict__ pr, const uint32_t* __restrict__ pim,
       float* __restrict__ out) {
    const int lane = threadIdx.x & 63;
    const int w    = threadIdx.x >> 6;       // wave id 0..3: owns 8 items
    const int il   = lane & 7;               // item-in-wave
    const int sub  = lane >> 3;              // 0..7
    const int cw   = sub >> 1;               // k-chunk: k in [cw*64, cw*64+64)
    const int h    = sub & 1;                // chain pair (2h, 2h+1); owns u_h
    const int item = blockIdx.x * 32 + w * 8 + il;

    __shared__ float sp[4][10];              // ath, ar, lth, lr per step

    if (threadIdx.x < 40) {
        const int a = threadIdx.x / 10, i = threadIdx.x % 10;
        const float* src = (a == 0) ? a_th_raw : (a == 1) ? a_r_raw
                         : (a == 2) ? l_th_raw : l_r_raw;
        const float v  = log1pf(expf(src[i]));           // verbatim round-1 expr
        const float hi = (a < 2) ? 0.2f : 1.0f;
        sp[a][i] = fminf(fmaxf(v, 1e-6f), hi);
    }

    // this thread's sign words (chain-major layout from pack_signs)
    const uint32_t br = pr [(size_t)item * 8 + sub];
    const uint32_t bi = pim[(size_t)item * 8 + sub];

    // u_own: h=0 -> atanh(clip(theta/60)); h=1 -> atanh(2*clip(r/2000)-1).
    // Per-component expressions verbatim; one atanhf on the selected arg.
    float y = th0[item] * (1.0f / 60.0f);
    y = fminf(fmaxf(y, -1.0f + 1e-6f), 1.0f - 1e-6f);
    float sR = r0[item] * (1.0f / 2000.0f);
    sR = fminf(fmaxf(sR, 1e-6f), 1.0f - 1e-6f);
    const float yR = 2.0f * sR - 1.0f;
    float u_own = atanhf(h ? yR : y);

    // chain-pair k seeds: exact small ints, identical values to baseline
    const float k0a = (float)(cw * 64 + 2 * h);
    const float k0b = (float)(cw * 64 + 2 * h + 1);

    __syncthreads();                          // sp[] ready (only barrier)

    for (int t = 0; t < 10; ++t) {
        // one tanh per lane; exchange to get both components (bit-copies)
        const float T_own = tanhf(u_own);
        const float T_oth = __shfl_xor(T_own, 8, 64);
        const float T0 = h ? T_oth : T_own;
        const float T1 = h ? T_own : T_oth;

        const float th_rad = (PI_F / 3.0f) * T0;          // 60*T0 deg -> rad
        const float sth = sinf(th_rad), cth = cosf(th_rad);
        const float r   = 1000.0f * (T1 + 1.0f);
        const float crev = 0.5f * sth - 2e-4f * r;        // revolutions per unit k

        // rotation step e^{i*2pi*4*crev}
        const float d4 = fract_(4.0f * crev);
        const v2f C4 = splat2(cos2pi_(d4));
        const v2f S4 = splat2(sin2pi_(d4));

        // seed the single chain pair (chains 2h, 2h+1 of chunk cw)
        const float rva = fract_(k0a * crev);
        const float rvb = fract_(k0b * crev);
        v2f c, s, kf, acc;
        c.x  = cos2pi_(rva);  c.y  = cos2pi_(rvb);
        s.x  = sin2pi_(rva);  s.y  = sin2pi_(rvb);
        kf.x = k0a;           kf.y = k0b;
        acc  = splat2(0.0f);

        const v2f mtwo = splat2(-2.0f);
        const v2f one  = splat2(1.0f);
        const v2f cub  = splat2(-(1.0f / 196608.0f));
        const v2f four = splat2(4.0f);

        #pragma unroll
        for (int j = 0; j < 16; ++j) {
            // chain A bit = j, chain B bit = 16+j  (compile-time shifts)
            const uint32_t mreA = (br << (31 - j)) & 0x80000000u;
            const uint32_t mreB = (br << (15 - j)) & 0x80000000u;
            const uint32_t mimA = (bi << (31 - j)) & 0x80000000u;
            const uint32_t mimB = (bi << (15 - j)) & 0x80000000u;
            const v2f cs = c, ss = s;
            v2f zc, zs;                                 // z_im*cos, z_re*sin
            zc.x = __uint_as_float(__float_as_uint(cs.x) ^ mimA);
            zc.y = __uint_as_float(__float_as_uint(cs.y) ^ mimB);
            zs.x = __uint_as_float(__float_as_uint(ss.x) ^ mreA);
            zs.y = __uint_as_float(__float_as_uint(ss.y) ^ mreB);
            const v2f w0 = zc - zs;
            // cubic sigma term: -sin(4phi)/786432 = -s*c*(1-2s^2)/196608
            const v2f u2 = ss * ss;
            const v2f t2 = __builtin_elementwise_fma(mtwo, u2, one);
            const v2f sc = ss * cs;
            const v2f v  = sc * t2;
            const v2f W  = __builtin_elementwise_fma(v, cub, w0 * 0.0625f);
            acc = __builtin_elementwise_fma(kf, W, acc);
            kf  = kf + four;
            // rotate phase by 4*crev revolutions
            const v2f tA = ss * S4;
            const v2f tB = cs * S4;
            c = __builtin_elementwise_fma(cs, C4, -tA);
            s = __builtin_elementwise_fma(ss, C4, tB);
        }
        // within-pair fold: A_{2h} + A_{2h+1}
        float S = acc.x + acc.y;
        // xor8: -> (A0+A1)+(A2+A3) = old chunk fold (commutation-exact)
        S += __shfl_xor(S, 8, 64);
        // xor16/32: -> (S0+S1)+(S2+S3) across chunks (commutation-exact)
        S += __shfl_xor(S, 16, 64);
        S += __shfl_xor(S, 32, 64);

        // tail, own component only. Associations verbatim:
        //   g0 = ((-(pi^2/3) * cth) * (1-T0^2)) * S
        //   g1 = ((0.4*pi) * (1-T1^2)) * S      (0.4f*PI_F folded at compile time)
        const float Ccth = -(PI_F * PI_F / 3.0f) * cth;
        const float coef = h ? (0.4f * PI_F) : Ccth;
        const float Tf   = 1.0f - T_own * T_own;
        const float g    = coef * Tf * S;
        const float alp  = sp[h][t];          // ath / ar
        const float lam  = sp[2 + h][t];      // lth / lr
        const float den  = fmaxf(fabsf(g), 1e-6f) + lam;
        float st = alp * g / den;
        st = fminf(fmaxf(st, -0.1f), 0.1f);
        u_own -= st;
    }

    // epilogue: one tanh; h=0 writes theta, h=1 writes r (chunk 0 only)
    const float tv  = tanhf(u_own);
    const float val = h ? 1000.0f * (tv + 1.0f) : 60.0f * tv;
    if (cw == 0) {
        out[2 * item + h] = val;
    }
}

extern "C" void kernel_launch(void* const* d_in, const int* in_sizes, int n_in,
                              void* d_out, int out_size, void* d_ws, size_t ws_size,
                              hipStream_t stream) {
    const float* zr   = (const float*)d_in[0];
    const float* zi   = (const float*)d_in[1];
    const float* th0  = (const float*)d_in[2];
    const float* r0   = (const float*)d_in[3];
    const float* athr = (const float*)d_in[4];
    const float* arr  = (const float*)d_in[5];
    const float* lthr = (const float*)d_in[6];
    const float* lrr  = (const float*)d_in[7];

    const int B = in_sizes[2];          // 32768

    uint32_t* pr  = (uint32_t*)d_ws;     // B*8 words = 1 MB
    uint32_t* pim = pr + (size_t)B * 8;  // B*8 words = 1 MB

    pack_signs<<<B / 4, 256, 0, stream>>>((const float4*)zr, (const float4*)zi,
                                          pr, pim);
    refine<<<B / 32, 256, 0, stream>>>(th0, r0, athr, arr, lthr, lrr,
                                       pr, pim, (float*)d_out);
}